// Round 6
// baseline (629.629 us; speedup 1.0000x reference)
//
#include <hip/hip_runtime.h>
#include <cmath>

#define BB 2
#define AA 5
#define CH 64
#define HH 128
#define WW 128
#define HW (HH*WW)
#define NIMG (BB*AA)

typedef __attribute__((ext_vector_type(8))) _Float16 half8;
typedef __attribute__((ext_vector_type(2))) _Float16 half2v;
typedef __attribute__((ext_vector_type(4))) float floatx4;
typedef unsigned int uint32;
typedef __attribute__((ext_vector_type(4))) uint32 uint4v;

__device__ inline half8 hzero() {
    half8 v;
#pragma unroll
    for (int e = 0; e < 8; ++e) v[e] = (_Float16)0.f;
    return v;
}

__device__ inline float fsigmoid(float x) {
    return __builtin_amdgcn_rcpf(1.f + __builtin_amdgcn_exp2f(-1.442695041f * x));
}
__device__ inline float ftanh(float x) {
    return 2.f * fsigmoid(2.f * x) - 1.f;
}

// ---------------------------------------------------------------------------
// feats fp32 planar [NIMG,64,H,W] -> NHWC f16 buffer channels 0..63
// ---------------------------------------------------------------------------
__global__ __launch_bounds__(256) void to_nhwc_kernel(
    const float* __restrict__ src, _Float16* __restrict__ dst)
{
    const int img = blockIdx.y;
    const int cg  = blockIdx.x & 7;
    const int pb  = blockIdx.x >> 3;
    const int p   = pb * 256 + threadIdx.x;
    const float* s = src + ((size_t)img * CH + cg * 8) * HW + p;
    half8 v;
#pragma unroll
    for (int e = 0; e < 8; ++e) v[e] = (_Float16)s[e * HW];
    *(half8*)(dst + ((size_t)img * HW + p) * 128 + cg * 8) = v;
}

// ---------------------------------------------------------------------------
// pack wx [192,128,3,3] fp32 -> f16 B-fragment layout:
// wp[cc][tap][gk][oc][e] : k = cc*32 + gk*8 + e, tap = ky*3+kx
// ---------------------------------------------------------------------------
__global__ __launch_bounds__(256) void pack_w_kernel(
    const float* __restrict__ wx, half8* __restrict__ wp)
{
    int idx = blockIdx.x * 256 + threadIdx.x;     // 4*9*4*192 = 27648
    if (idx >= 4 * 9 * 4 * 192) return;
    int oc = idx % 192; int r = idx / 192;
    int gk = r & 3; r >>= 2; int tap = r % 9; int cc = r / 9;
    int ky = tap / 3, kx = tap % 3;
    half8 v;
#pragma unroll
    for (int e = 0; e < 8; ++e)
        v[e] = (_Float16)wx[(((size_t)oc * 128 + cc * 32 + gk * 8 + e) * 3 + ky) * 3 + kx];
    wp[idx] = v;
}

// ---------------------------------------------------------------------------
// warp_mean v2: one block = 16x8 px tile x ALL 64 ch, one (b,i).
// Phase B (stage-1 rotate-sample): 256 thr = 32 pts x 8 ch-slices; 8
// consecutive lanes cover one gather point's 128 B -> coalesced tap reads.
// f-tile stored as packed half2 in LDS [c2=32][row=9][col=18].
// Phase C (stage-2 const 2x2 combine + j-accumulate): v_pk_fma_f16,
// thread = (px, ch-half), 16 half2 acc regs.
// grid: x = 128 tiles (16x8), z = b*A+i
// ---------------------------------------------------------------------------
__global__ __launch_bounds__(256, 5) void warp_mean_kernel(
    const _Float16* __restrict__ nh,     // [NIMG, HW, 128]
    const float* __restrict__ trans,     // [B, A, A, 4, 4]
    _Float16* __restrict__ nhw)          // same buffer, writes ch 64..127
{
    __shared__ uint32 f_lds[32 * 9 * 18];   // 20736 B

    const int tile = blockIdx.x;
    const int tx0 = (tile & 7) * 16;
    const int ty0 = (tile >> 3) * 8;
    const int bi  = blockIdx.z;
    const int b   = bi / AA, i = bi % AA;
    const int tid = threadIdx.x;

    // phase B mapping
    const int slc = tid & 7;        // 16 B ch-slice
    const int ptb = tid >> 3;       // 0..31
    // phase C mapping
    const int col = tid & 15;
    const int row = (tid >> 4) & 7;
    const int chh = tid >> 7;       // ch-half: 0 -> ch0..31, 1 -> ch32..63

    half2v acc[16];
#pragma unroll
    for (int c = 0; c < 16; ++c) acc[c] = (half2v)(_Float16)0.f;

    for (int j = 0; j < AA; ++j) {
        if (j == i) continue;
        const float* t = trans + (((size_t)b * AA + i) * AA + j) * 16;
        const float t00 = t[0], t01 = t[1], t03 = t[3];
        const float t10 = t[4], t11 = t[5], t13 = t[7];
        const float dxs = 2.f * t03;
        const float dys = -2.f * t13;
        const float sxf = floorf(dxs), syf = floorf(dys);
        const int sx = (int)sxf, sy = (int)syf;
        const float fx = dxs - sxf, fy = dys - syf;
        const _Float16* srcj = nh + (size_t)(b * AA + j) * HW * 128 + slc * 8;

        __syncthreads();   // prior phase-C reads complete
        // ---- phase B: stage f on 9x17 grid, all 64 ch ----
#pragma unroll
        for (int it = 0; it < 5; ++it) {
            const int pt = it * 32 + ptb;
            if (pt < 153) {
                const int prow = pt / 17;
                const int pcol = pt - prow * 17;
                const int qx = tx0 + sx + pcol;
                const int qy = ty0 + sy + prow;
                float e[8];
#pragma unroll
                for (int k = 0; k < 8; ++k) e[k] = 0.f;
                if (((unsigned)qx < (unsigned)WW) & ((unsigned)qy < (unsigned)HH)) {
                    const float xn = (2 * qx + 1) * (1.0f / WW) - 1.f;
                    const float yn = (2 * qy + 1) * (1.0f / HH) - 1.f;
                    const float px = 64.f * (t00 * xn + t01 * yn) + 63.5f;
                    const float py = 64.f * (t10 * xn + t11 * yn) + 63.5f;
                    const float x0f = floorf(px), y0f = floorf(py);
                    const int x0 = (int)x0f, y0 = (int)y0f;
                    const float wx1 = px - x0f, wx0 = 1.f - wx1;
                    const float wy1 = py - y0f, wy0 = 1.f - wy1;
                    const bool vx0 = (x0 >= 0) & (x0 < WW);
                    const bool vx1 = (x0 + 1 >= 0) & (x0 + 1 < WW);
                    const bool vy0 = (y0 >= 0) & (y0 < HH);
                    const bool vy1 = (y0 + 1 >= 0) & (y0 + 1 < HH);
                    const int cx0 = min(max(x0, 0), WW - 1);
                    const int cx1 = min(max(x0 + 1, 0), WW - 1);
                    const int cy0 = min(max(y0, 0), HH - 1);
                    const int cy1 = min(max(y0 + 1, 0), HH - 1);
                    const float w00 = (vx0 & vy0) ? wx0 * wy0 : 0.f;
                    const float w01 = (vx1 & vy0) ? wx1 * wy0 : 0.f;
                    const float w10 = (vx0 & vy1) ? wx0 * wy1 : 0.f;
                    const float w11 = (vx1 & vy1) ? wx1 * wy1 : 0.f;
                    const half8 A = *(const half8*)(srcj + ((size_t)cy0 * WW + cx0) * 128);
                    const half8 Bv = *(const half8*)(srcj + ((size_t)cy0 * WW + cx1) * 128);
                    const half8 Cv = *(const half8*)(srcj + ((size_t)cy1 * WW + cx0) * 128);
                    const half8 D = *(const half8*)(srcj + ((size_t)cy1 * WW + cx1) * 128);
#pragma unroll
                    for (int k = 0; k < 8; ++k)
                        e[k] = w00 * (float)A[k] + w01 * (float)Bv[k]
                             + w10 * (float)Cv[k] + w11 * (float)D[k];
                }
                const int lb = slc * 4 * 162 + prow * 18 + pcol;
#pragma unroll
                for (int k = 0; k < 4; ++k) {
                    half2v p;
                    p[0] = (_Float16)e[2 * k];
                    p[1] = (_Float16)e[2 * k + 1];
                    f_lds[lb + k * 162] = __builtin_bit_cast(uint32, p);
                }
            }
        }
        __syncthreads();

        // ---- phase C: constant 2x2 combine, packed f16 ----
        const float wAf = (1.f - fx) * (1.f - fy);
        const float wBf = fx * (1.f - fy);
        const float wCf = (1.f - fx) * fy;
        const float wDf = fx * fy;
        half2v wA2 = (half2v)(_Float16)wAf;
        half2v wB2 = (half2v)(_Float16)wBf;
        half2v wC2 = (half2v)(_Float16)wCf;
        half2v wD2 = (half2v)(_Float16)wDf;
        const uint32* fp0 = f_lds + (chh * 16) * 162 + row * 18 + col;
#pragma unroll
        for (int c = 0; c < 16; ++c) {
            const uint32* fp = fp0 + c * 162;
            const half2v v00 = __builtin_bit_cast(half2v, fp[0]);
            const half2v v01 = __builtin_bit_cast(half2v, fp[1]);
            const half2v v10 = __builtin_bit_cast(half2v, fp[18]);
            const half2v v11 = __builtin_bit_cast(half2v, fp[19]);
            acc[c] += v00 * wA2 + v01 * wB2 + v10 * wC2 + v11 * wD2;
        }
    }

    const half2v q = (half2v)(_Float16)0.25f;   // 1/(A-1)
    uint32 os[16];
#pragma unroll
    for (int c = 0; c < 16; ++c) os[c] = __builtin_bit_cast(uint32, acc[c] * q);
    uint4v* dst = (uint4v*)(nhw + ((size_t)bi * HW + (ty0 + row) * WW + tx0 + col) * 128
                            + 64 + chh * 32);
#pragma unroll
    for (int k = 0; k < 4; ++k)
        dst[k] = (uint4v){os[4 * k], os[4 * k + 1], os[4 * k + 2], os[4 * k + 3]};
}

// ---------------------------------------------------------------------------
// MFMA implicit-GEMM 3x3 conv + fused GRU gating.
// v6: M-tile doubled to 128 px (16x8) -> halves per-dispatch L2 weight
// re-read traffic (1.1 GB -> 0.57 GB). Barrier-free K-loop, b-frags from
// global (L2) with depth-1 register prefetch. launch_bounds(256,3) caps
// VGPR ~170 to hold 3 waves/SIMD.
// ---------------------------------------------------------------------------
__global__ __launch_bounds__(256, 3) void conv_gru_mfma(
    const _Float16* __restrict__ in,    // [NIMG, HW, 128]
    const half8* __restrict__ wp,       // packed weights [36][768]
    const float* __restrict__ bx,       // [192]
    const float* __restrict__ bh,       // [192]
    float* __restrict__ out_f32,        // [NIMG,64,H,W] or null
    _Float16* __restrict__ out_f16)     // [NIMG,HW,128] ch0..63 or null
{
    __shared__ half8 lds_in[16 * 10 * 18];   // [g=16][row=10][col=18], 46080 B

    const int tid = threadIdx.x;
    const int img = blockIdx.z;
    const int x0 = (blockIdx.x & 7) * 16;       // 8 x-tiles
    const int y0 = (blockIdx.x >> 3) * 8;       // 16 y-tiles
    const int w   = tid >> 6;                   // wave -> c-range w*16..+15
    const int ln  = tid & 15;
    const int kq  = (tid & 63) >> 4;

    // ---- stage 10x18 halo x 128ch (only barrier in the kernel) ----
    const _Float16* inimg = in + (size_t)img * HW * 128;
    for (int f = tid; f < 2880; f += 256) {
        const int g = f / 180; const int r = f % 180;
        const int prow = r / 18; const int pcol = r % 18;
        const int y = y0 + prow - 1, x = x0 + pcol - 1;
        half8 v = hzero();
        if ((unsigned)x < (unsigned)WW && (unsigned)y < (unsigned)HH)
            v = *(const half8*)(inimg + ((size_t)y * WW + x) * 128 + g * 8);
        lds_in[f] = v;
    }

    floatx4 acc[8][3];     // [y-row][gate]
#pragma unroll
    for (int s = 0; s < 8; ++s)
#pragma unroll
        for (int t = 0; t < 3; ++t)
#pragma unroll
            for (int r = 0; r < 4; ++r) acc[s][t][r] = 0.f;

    __syncthreads();

    // ---- barrier-free K-loop: 36 steps (4 ci-chunks x 9 taps) ----
    const half8* wbase = wp + kq * 192 + w * 16 + ln;
    half8 bnx[3];
#pragma unroll
    for (int t = 0; t < 3; ++t) bnx[t] = wbase[t * 64];

#pragma unroll
    for (int s = 0; s < 36; ++s) {
        const int cc = s / 9, tap = s - cc * 9;
        const int dy = tap / 3, dx = tap - dy * 3;
        half2v dummy;
        half8 bcur[3];
#pragma unroll
        for (int t = 0; t < 3; ++t) bcur[t] = bnx[t];
        if (s + 1 < 36) {
            const half8* wsrc = wbase + (size_t)(s + 1) * 768;
#pragma unroll
            for (int t = 0; t < 3; ++t) bnx[t] = wsrc[t * 64];
        }
        half8 a[8];
#pragma unroll
        for (int t = 0; t < 8; ++t)
            a[t] = lds_in[((cc * 4 + kq) * 10 + t + dy) * 18 + ln + dx];
#pragma unroll
        for (int t = 0; t < 8; ++t)
#pragma unroll
            for (int u = 0; u < 3; ++u)
                acc[t][u] = __builtin_amdgcn_mfma_f32_16x16x32_f16(a[t], bcur[u], acc[t][u], 0, 0, 0);
    }

    // epilogue: GRU gating. D layout: col(oc%16)=ln, row(x)=kq*4+reg.
    const int c = w * 16 + ln;                  // 0..63
    const float bxr = bx[c] + bh[c];
    const float bxz = bx[64 + c] + bh[64 + c];
    const float bxn = bx[128 + c];
    const float bnn = bh[128 + c];
#pragma unroll
    for (int s = 0; s < 8; ++s) {
        const int y = y0 + s;
#pragma unroll
        for (int reg = 0; reg < 4; ++reg) {
            const int x = x0 + kq * 4 + reg;
            const float xr = acc[s][0][reg] + bxr;
            const float xz = acc[s][1][reg] + bxz;
            const float xn = acc[s][2][reg] + bxn;
            const float rg = fsigmoid(xr);
            const float zg = fsigmoid(xz);
            const float n  = ftanh(xn + rg * bnn);
            const float h  = (1.f - zg) * n;
            if (out_f32)
                out_f32[((size_t)img * CH + c) * HW + y * WW + x] = h;
            else
                out_f16[((size_t)img * HW + y * WW + x) * 128 + c] = (_Float16)h;
        }
    }
}

// ---------------------------------------------------------------------------
extern "C" void kernel_launch(void* const* d_in, const int* in_sizes, int n_in,
                              void* d_out, int out_size, void* d_ws, size_t ws_size,
                              hipStream_t stream) {
    const float* feats = (const float*)d_in[0];
    const float* trans = (const float*)d_in[1];
    const float* wx    = (const float*)d_in[2];
    // d_in[3] = wh (unused: h0 = 0)
    const float* bx    = (const float*)d_in[4];
    const float* bh    = (const float*)d_in[5];
    float* out = (float*)d_out;

    char* ws = (char*)d_ws;
    half8*    wpack = (half8*)ws;                              // 442,368 B
    _Float16* B1 = (_Float16*)(ws + 442368);                   // 40 MB NHWC f16
    _Float16* B2 = (_Float16*)(ws + 442368 + (size_t)NIMG * HW * 128 * 2);

    pack_w_kernel<<<108, 256, 0, stream>>>(wx, wpack);
    to_nhwc_kernel<<<dim3(512, NIMG), 256, 0, stream>>>(feats, B1);

    dim3 wgrid(128, 1, NIMG);      // 16x8 px tiles
    dim3 cgrid(128, 1, NIMG);      // 16x8 px tiles

    // iteration 1
    warp_mean_kernel<<<wgrid, 256, 0, stream>>>(B1, trans, B1);
    conv_gru_mfma<<<cgrid, 256, 0, stream>>>(B1, wpack, bx, bh, nullptr, B2);
    // iteration 2
    warp_mean_kernel<<<wgrid, 256, 0, stream>>>(B2, trans, B2);
    conv_gru_mfma<<<cgrid, 256, 0, stream>>>(B2, wpack, bx, bh, out, nullptr);
}

// Round 7
// 338.798 us; speedup vs baseline: 1.8584x; 1.8584x over previous
//
#include <hip/hip_runtime.h>
#include <cmath>

#define BB 2
#define AA 5
#define CH 64
#define HH 128
#define WW 128
#define HW (HH*WW)
#define NIMG (BB*AA)

typedef __attribute__((ext_vector_type(8))) _Float16 half8;
typedef __attribute__((ext_vector_type(2))) _Float16 half2v;
typedef __attribute__((ext_vector_type(4))) float floatx4;
typedef unsigned int uint32;
typedef __attribute__((ext_vector_type(4))) uint32 uint4v;

__device__ inline half8 hzero() {
    half8 v;
#pragma unroll
    for (int e = 0; e < 8; ++e) v[e] = (_Float16)0.f;
    return v;
}

__device__ inline float fsigmoid(float x) {
    return __builtin_amdgcn_rcpf(1.f + __builtin_amdgcn_exp2f(-1.442695041f * x));
}
__device__ inline float ftanh(float x) {
    return 2.f * fsigmoid(2.f * x) - 1.f;
}

// ---------------------------------------------------------------------------
// feats fp32 planar [NIMG,64,H,W] -> NHWC f16 buffer channels 0..63
// ---------------------------------------------------------------------------
__global__ __launch_bounds__(256) void to_nhwc_kernel(
    const float* __restrict__ src, _Float16* __restrict__ dst)
{
    const int img = blockIdx.y;
    const int cg  = blockIdx.x & 7;
    const int pb  = blockIdx.x >> 3;
    const int p   = pb * 256 + threadIdx.x;
    const float* s = src + ((size_t)img * CH + cg * 8) * HW + p;
    half8 v;
#pragma unroll
    for (int e = 0; e < 8; ++e) v[e] = (_Float16)s[e * HW];
    *(half8*)(dst + ((size_t)img * HW + p) * 128 + cg * 8) = v;
}

// ---------------------------------------------------------------------------
// pack wx [192,128,3,3] fp32 -> f16 B-fragment layout:
// wp[cc][tap][gk][oc][e] : k = cc*32 + gk*8 + e, tap = ky*3+kx
// ---------------------------------------------------------------------------
__global__ __launch_bounds__(256) void pack_w_kernel(
    const float* __restrict__ wx, half8* __restrict__ wp)
{
    int idx = blockIdx.x * 256 + threadIdx.x;     // 4*9*4*192 = 27648
    if (idx >= 4 * 9 * 4 * 192) return;
    int oc = idx % 192; int r = idx / 192;
    int gk = r & 3; r >>= 2; int tap = r % 9; int cc = r / 9;
    int ky = tap / 3, kx = tap % 3;
    half8 v;
#pragma unroll
    for (int e = 0; e < 8; ++e)
        v[e] = (_Float16)wx[(((size_t)oc * 128 + cc * 32 + gk * 8 + e) * 3 + ky) * 3 + kx];
    wp[idx] = v;
}

// ---------------------------------------------------------------------------
// warp_mean v2 (unchanged from R6 — verified ~45 µs): one block = 16x8 px
// tile x ALL 64 ch. Phase B: 8 consecutive lanes = one gather point's 128 B
// -> coalesced. Phase C: packed-f16 2x2 combine + j-accumulate.
// ---------------------------------------------------------------------------
__global__ __launch_bounds__(256, 5) void warp_mean_kernel(
    const _Float16* __restrict__ nh,     // [NIMG, HW, 128]
    const float* __restrict__ trans,     // [B, A, A, 4, 4]
    _Float16* __restrict__ nhw)          // same buffer, writes ch 64..127
{
    __shared__ uint32 f_lds[32 * 9 * 18];   // 20736 B

    const int tile = blockIdx.x;
    const int tx0 = (tile & 7) * 16;
    const int ty0 = (tile >> 3) * 8;
    const int bi  = blockIdx.z;
    const int b   = bi / AA, i = bi % AA;
    const int tid = threadIdx.x;

    const int slc = tid & 7;
    const int ptb = tid >> 3;
    const int col = tid & 15;
    const int row = (tid >> 4) & 7;
    const int chh = tid >> 7;

    half2v acc[16];
#pragma unroll
    for (int c = 0; c < 16; ++c) acc[c] = (half2v)(_Float16)0.f;

    for (int j = 0; j < AA; ++j) {
        if (j == i) continue;
        const float* t = trans + (((size_t)b * AA + i) * AA + j) * 16;
        const float t00 = t[0], t01 = t[1], t03 = t[3];
        const float t10 = t[4], t11 = t[5], t13 = t[7];
        const float dxs = 2.f * t03;
        const float dys = -2.f * t13;
        const float sxf = floorf(dxs), syf = floorf(dys);
        const int sx = (int)sxf, sy = (int)syf;
        const float fx = dxs - sxf, fy = dys - syf;
        const _Float16* srcj = nh + (size_t)(b * AA + j) * HW * 128 + slc * 8;

        __syncthreads();
#pragma unroll
        for (int it = 0; it < 5; ++it) {
            const int pt = it * 32 + ptb;
            if (pt < 153) {
                const int prow = pt / 17;
                const int pcol = pt - prow * 17;
                const int qx = tx0 + sx + pcol;
                const int qy = ty0 + sy + prow;
                float e[8];
#pragma unroll
                for (int k = 0; k < 8; ++k) e[k] = 0.f;
                if (((unsigned)qx < (unsigned)WW) & ((unsigned)qy < (unsigned)HH)) {
                    const float xn = (2 * qx + 1) * (1.0f / WW) - 1.f;
                    const float yn = (2 * qy + 1) * (1.0f / HH) - 1.f;
                    const float px = 64.f * (t00 * xn + t01 * yn) + 63.5f;
                    const float py = 64.f * (t10 * xn + t11 * yn) + 63.5f;
                    const float x0f = floorf(px), y0f = floorf(py);
                    const int x0 = (int)x0f, y0 = (int)y0f;
                    const float wx1 = px - x0f, wx0 = 1.f - wx1;
                    const float wy1 = py - y0f, wy0 = 1.f - wy1;
                    const bool vx0 = (x0 >= 0) & (x0 < WW);
                    const bool vx1 = (x0 + 1 >= 0) & (x0 + 1 < WW);
                    const bool vy0 = (y0 >= 0) & (y0 < HH);
                    const bool vy1 = (y0 + 1 >= 0) & (y0 + 1 < HH);
                    const int cx0 = min(max(x0, 0), WW - 1);
                    const int cx1 = min(max(x0 + 1, 0), WW - 1);
                    const int cy0 = min(max(y0, 0), HH - 1);
                    const int cy1 = min(max(y0 + 1, 0), HH - 1);
                    const float w00 = (vx0 & vy0) ? wx0 * wy0 : 0.f;
                    const float w01 = (vx1 & vy0) ? wx1 * wy0 : 0.f;
                    const float w10 = (vx0 & vy1) ? wx0 * wy1 : 0.f;
                    const float w11 = (vx1 & vy1) ? wx1 * wy1 : 0.f;
                    const half8 A = *(const half8*)(srcj + ((size_t)cy0 * WW + cx0) * 128);
                    const half8 Bv = *(const half8*)(srcj + ((size_t)cy0 * WW + cx1) * 128);
                    const half8 Cv = *(const half8*)(srcj + ((size_t)cy1 * WW + cx0) * 128);
                    const half8 D = *(const half8*)(srcj + ((size_t)cy1 * WW + cx1) * 128);
#pragma unroll
                    for (int k = 0; k < 8; ++k)
                        e[k] = w00 * (float)A[k] + w01 * (float)Bv[k]
                             + w10 * (float)Cv[k] + w11 * (float)D[k];
                }
                const int lb = slc * 4 * 162 + prow * 18 + pcol;
#pragma unroll
                for (int k = 0; k < 4; ++k) {
                    half2v p;
                    p[0] = (_Float16)e[2 * k];
                    p[1] = (_Float16)e[2 * k + 1];
                    f_lds[lb + k * 162] = __builtin_bit_cast(uint32, p);
                }
            }
        }
        __syncthreads();

        const float wAf = (1.f - fx) * (1.f - fy);
        const float wBf = fx * (1.f - fy);
        const float wCf = (1.f - fx) * fy;
        const float wDf = fx * fy;
        half2v wA2 = (half2v)(_Float16)wAf;
        half2v wB2 = (half2v)(_Float16)wBf;
        half2v wC2 = (half2v)(_Float16)wCf;
        half2v wD2 = (half2v)(_Float16)wDf;
        const uint32* fp0 = f_lds + (chh * 16) * 162 + row * 18 + col;
#pragma unroll
        for (int c = 0; c < 16; ++c) {
            const uint32* fp = fp0 + c * 162;
            const half2v v00 = __builtin_bit_cast(half2v, fp[0]);
            const half2v v01 = __builtin_bit_cast(half2v, fp[1]);
            const half2v v10 = __builtin_bit_cast(half2v, fp[18]);
            const half2v v11 = __builtin_bit_cast(half2v, fp[19]);
            acc[c] += v00 * wA2 + v01 * wB2 + v10 * wC2 + v11 * wD2;
        }
    }

    const half2v q = (half2v)(_Float16)0.25f;   // 1/(A-1)
    uint32 os[16];
#pragma unroll
    for (int c = 0; c < 16; ++c) os[c] = __builtin_bit_cast(uint32, acc[c] * q);
    uint4v* dst = (uint4v*)(nhw + ((size_t)bi * HW + (ty0 + row) * WW + tx0 + col) * 128
                            + 64 + chh * 32);
#pragma unroll
    for (int k = 0; k < 4; ++k)
        dst[k] = (uint4v){os[4 * k], os[4 * k + 1], os[4 * k + 2], os[4 * k + 3]};
}

// ---------------------------------------------------------------------------
// MFMA implicit-GEMM 3x3 conv + fused GRU gating.
// v7: R5 structure (64 px tile, acc[4][3]=48 VGPR, no spill) + DEPTH-2
// register prefetch of b-frags (covers ~116 cyc of the ~200-cyc L2 latency
// that depth-1's 58-cyc shadow left exposed).
// ---------------------------------------------------------------------------
__global__ __launch_bounds__(256, 4) void conv_gru_mfma(
    const _Float16* __restrict__ in,    // [NIMG, HW, 128]
    const half8* __restrict__ wp,       // packed weights [36][768]
    const float* __restrict__ bx,       // [192]
    const float* __restrict__ bh,       // [192]
    float* __restrict__ out_f32,        // [NIMG,64,H,W] or null
    _Float16* __restrict__ out_f16)     // [NIMG,HW,128] ch0..63 or null
{
    __shared__ half8 lds_in[16 * 6 * 18];    // 27648 B

    const int tid = threadIdx.x;
    const int img = blockIdx.z;
    const int x0 = (blockIdx.x & 7) * 16;       // 8 x-tiles
    const int y0 = (blockIdx.x >> 3) * 4;       // 32 y-tiles
    const int w   = tid >> 6;                   // wave -> c-range w*16..+15
    const int ln  = tid & 15;
    const int kq  = (tid & 63) >> 4;

    // ---- stage 6x18 halo x 128ch (only barrier in the kernel) ----
    const _Float16* inimg = in + (size_t)img * HW * 128;
    for (int f = tid; f < 1728; f += 256) {
        const int g = f / 108; const int r = f % 108;
        const int row = r / 18; const int col = r % 18;
        const int y = y0 + row - 1, x = x0 + col - 1;
        half8 v = hzero();
        if ((unsigned)x < (unsigned)WW && (unsigned)y < (unsigned)HH)
            v = *(const half8*)(inimg + ((size_t)y * WW + x) * 128 + g * 8);
        lds_in[f] = v;
    }

    floatx4 acc[4][3];     // [y-row][gate]
#pragma unroll
    for (int s = 0; s < 4; ++s)
#pragma unroll
        for (int t = 0; t < 3; ++t)
#pragma unroll
            for (int r = 0; r < 4; ++r) acc[s][t][r] = 0.f;

    __syncthreads();

    // ---- barrier-free K-loop, depth-2 b prefetch ----
    const half8* wbase = wp + kq * 192 + w * 16 + ln;
    half8 bp0[3], bp1[3];
#pragma unroll
    for (int t = 0; t < 3; ++t) bp0[t] = wbase[t * 64];
#pragma unroll
    for (int t = 0; t < 3; ++t) bp1[t] = wbase[768 + t * 64];

#pragma unroll
    for (int s = 0; s < 36; ++s) {
        const int cc = s / 9, tap = s - cc * 9;
        const int dy = tap / 3, dx = tap - dy * 3;
        half8 bcur[3];
#pragma unroll
        for (int t = 0; t < 3; ++t) { bcur[t] = bp0[t]; bp0[t] = bp1[t]; }
        if (s + 2 < 36) {
            const half8* wsrc = wbase + (size_t)(s + 2) * 768;
#pragma unroll
            for (int t = 0; t < 3; ++t) bp1[t] = wsrc[t * 64];
        }
        half8 a[4];
#pragma unroll
        for (int t = 0; t < 4; ++t)
            a[t] = lds_in[((cc * 4 + kq) * 6 + t + dy) * 18 + ln + dx];
#pragma unroll
        for (int t = 0; t < 4; ++t)
#pragma unroll
            for (int u = 0; u < 3; ++u)
                acc[t][u] = __builtin_amdgcn_mfma_f32_16x16x32_f16(a[t], bcur[u], acc[t][u], 0, 0, 0);
    }

    // epilogue: GRU gating. D layout: col(oc%16)=ln, row(x)=kq*4+reg.
    const int c = w * 16 + ln;                  // 0..63
    const float bxr = bx[c] + bh[c];
    const float bxz = bx[64 + c] + bh[64 + c];
    const float bxn = bx[128 + c];
    const float bnn = bh[128 + c];
#pragma unroll
    for (int s = 0; s < 4; ++s) {
        const int y = y0 + s;
#pragma unroll
        for (int reg = 0; reg < 4; ++reg) {
            const int x = x0 + kq * 4 + reg;
            const float xr = acc[s][0][reg] + bxr;
            const float xz = acc[s][1][reg] + bxz;
            const float xn = acc[s][2][reg] + bxn;
            const float rg = fsigmoid(xr);
            const float zg = fsigmoid(xz);
            const float n  = ftanh(xn + rg * bnn);
            const float h  = (1.f - zg) * n;
            if (out_f32)
                out_f32[((size_t)img * CH + c) * HW + y * WW + x] = h;
            else
                out_f16[((size_t)img * HW + y * WW + x) * 128 + c] = (_Float16)h;
        }
    }
}

// ---------------------------------------------------------------------------
extern "C" void kernel_launch(void* const* d_in, const int* in_sizes, int n_in,
                              void* d_out, int out_size, void* d_ws, size_t ws_size,
                              hipStream_t stream) {
    const float* feats = (const float*)d_in[0];
    const float* trans = (const float*)d_in[1];
    const float* wx    = (const float*)d_in[2];
    // d_in[3] = wh (unused: h0 = 0)
    const float* bx    = (const float*)d_in[4];
    const float* bh    = (const float*)d_in[5];
    float* out = (float*)d_out;

    char* ws = (char*)d_ws;
    half8*    wpack = (half8*)ws;                              // 442,368 B
    _Float16* B1 = (_Float16*)(ws + 442368);                   // 40 MB NHWC f16
    _Float16* B2 = (_Float16*)(ws + 442368 + (size_t)NIMG * HW * 128 * 2);

    pack_w_kernel<<<108, 256, 0, stream>>>(wx, wpack);
    to_nhwc_kernel<<<dim3(512, NIMG), 256, 0, stream>>>(feats, B1);

    dim3 wgrid(128, 1, NIMG);      // warp_mean: 16x8 px tiles
    dim3 cgrid(256, 1, NIMG);      // conv: 16x4 px tiles (8 x 32)

    // iteration 1
    warp_mean_kernel<<<wgrid, 256, 0, stream>>>(B1, trans, B1);
    conv_gru_mfma<<<cgrid, 256, 0, stream>>>(B1, wpack, bx, bh, nullptr, B2);
    // iteration 2
    warp_mean_kernel<<<wgrid, 256, 0, stream>>>(B2, trans, B2);
    conv_gru_mfma<<<cgrid, 256, 0, stream>>>(B2, wpack, bx, bh, out, nullptr);
}